// Round 1
// baseline (1776.959 us; speedup 1.0000x reference)
//
#include <hip/hip_runtime.h>
#include <cstdint>
#include <cstddef>
#include <cmath>

#define NN   100000   // nodes per graph
#define NE   1600000  // edges per graph
#define DD   64       // feature dim
#define NG   4        // graphs
#define NB_  32       // batch
#define NL   50       // candidate list length
#define NCL  2        // attention layers per stack
#define SCAN_NB 49    // ceil(NN/2048)

// ---------------------------------------------------------------- CSR build
__global__ __launch_bounds__(256) void k_hist(const int* __restrict__ dst,
                                              int* __restrict__ cnt, int g0) {
    const int gy = blockIdx.y;
    const int* d = dst + (size_t)(g0 + gy) * NE;
    int* c = cnt + (size_t)gy * (NN + 1);
    int e = blockIdx.x * 256 + threadIdx.x;
    if (e < NE) atomicAdd(&c[d[e]], 1);
}

__global__ __launch_bounds__(256) void k_scan1(const int* __restrict__ cnt,
                                               int* __restrict__ part) {
    const int gy = blockIdx.y;
    const int* c = cnt + (size_t)gy * (NN + 1);
    __shared__ int sh[256];
    const int tid = threadIdx.x;
    int base = blockIdx.x * 2048 + tid * 8;
    int s = 0;
    for (int i = 0; i < 8; ++i) { int idx = base + i; if (idx < NN) s += c[idx]; }
    sh[tid] = s; __syncthreads();
    for (int off = 128; off > 0; off >>= 1) {
        if (tid < off) sh[tid] += sh[tid + off];
        __syncthreads();
    }
    if (tid == 0) part[gy * 64 + blockIdx.x] = sh[0];
}

__global__ __launch_bounds__(64) void k_scan2(int* __restrict__ part,
                                              int* __restrict__ row_off) {
    const int gy = blockIdx.y;
    if (threadIdx.x == 0) {
        int* p = part + gy * 64;
        int run = 0;
        for (int i = 0; i < SCAN_NB; ++i) { int t = p[i]; p[i] = run; run += t; }
        row_off[(size_t)gy * (NN + 1) + NN] = run;  // == NE
    }
}

__global__ __launch_bounds__(256) void k_scan3(const int* __restrict__ cnt,
                                               const int* __restrict__ part,
                                               int* __restrict__ row_off,
                                               int* __restrict__ cursor) {
    const int gy = blockIdx.y;
    const int* c = cnt + (size_t)gy * (NN + 1);
    int* ro = row_off + (size_t)gy * (NN + 1);
    int* cu = cursor + (size_t)gy * NN;
    __shared__ int sh[256];
    const int tid = threadIdx.x;
    int base = blockIdx.x * 2048 + tid * 8;
    int vals[8];
    int s = 0;
    for (int i = 0; i < 8; ++i) {
        int idx = base + i;
        int v = (idx < NN) ? c[idx] : 0;
        vals[i] = v; s += v;
    }
    sh[tid] = s; __syncthreads();
    for (int off = 1; off < 256; off <<= 1) {
        int t = (tid >= off) ? sh[tid - off] : 0;
        __syncthreads();
        sh[tid] += t;
        __syncthreads();
    }
    int excl = sh[tid] - s;
    int run = part[gy * 64 + blockIdx.x] + excl;
    for (int i = 0; i < 8; ++i) {
        int idx = base + i;
        if (idx < NN) { ro[idx] = run; cu[idx] = run; run += vals[i]; }
    }
}

__global__ __launch_bounds__(256) void k_scatter(const int* __restrict__ src,
                                                 const int* __restrict__ dst,
                                                 const float* __restrict__ ew,
                                                 int* __restrict__ cursor,
                                                 int* __restrict__ ss,
                                                 float* __restrict__ ee, int g0) {
    const int gy = blockIdx.y;
    const int g = g0 + gy;
    int e = blockIdx.x * 256 + threadIdx.x;
    if (e < NE) {
        int d = dst[(size_t)g * NE + e];
        int p = atomicAdd(&cursor[(size_t)gy * NN + d], 1);
        ss[(size_t)gy * NE + p] = src[(size_t)g * NE + e];
        ee[(size_t)gy * NE + p] = ew[(size_t)g * NE + e];
    }
}

// ---------------------------------------------------------------- fused SAGE conv (all nodes, layer 1, relu)
__global__ __launch_bounds__(256) void k_conv_full(
    const float* __restrict__ emb, const int* __restrict__ row_off,
    const int* __restrict__ srcs, const float* __restrict__ ews,
    const float* __restrict__ Wsf, const float* __restrict__ Wng,
    const float* __restrict__ bias, float* __restrict__ outh, int g0)
{
    const int gy = blockIdx.y;
    const int g = g0 + gy;
    const float* feat = emb + (size_t)g * NN * DD;
    const int* ro = row_off + (size_t)gy * (NN + 1);
    const int* ss = srcs + (size_t)gy * NE;
    const float* ee = ews + (size_t)gy * NE;
    float* og = outh + (size_t)gy * NN * DD;
    const int lane = threadIdx.x & 63;
    const int wid = threadIdx.x >> 6;

    float wsr[DD], wnr[DD];
    {
        const float* wsp = Wsf + (size_t)g * DD * DD + (size_t)lane * DD;
        const float* wnp = Wng + (size_t)g * DD * DD + (size_t)lane * DD;
#pragma unroll
        for (int k4 = 0; k4 < 16; ++k4) {
            float4 a = *(const float4*)(wsp + 4 * k4);
            wsr[4 * k4 + 0] = a.x; wsr[4 * k4 + 1] = a.y; wsr[4 * k4 + 2] = a.z; wsr[4 * k4 + 3] = a.w;
            float4 c = *(const float4*)(wnp + 4 * k4);
            wnr[4 * k4 + 0] = c.x; wnr[4 * k4 + 1] = c.y; wnr[4 * k4 + 2] = c.z; wnr[4 * k4 + 3] = c.w;
        }
    }
    const float bv = bias[(size_t)g * DD + lane];

    __shared__ __attribute__((aligned(16))) float fs[4][DD];
    __shared__ __attribute__((aligned(16))) float ns[4][DD];

    const int wglob = blockIdx.x * 4 + wid;
    const int wstep = gridDim.x * 4;
    for (int n = wglob; n < NN; n += wstep) {
        const int e0 = ro[n], e1 = ro[n + 1];
        float acc = 0.f;
        int e = e0;
        for (; e + 1 < e1; e += 2) {
            int s0 = ss[e], s1 = ss[e + 1];
            float w0 = ee[e], w1 = ee[e + 1];
            float f0 = feat[(size_t)s0 * DD + lane];
            float f1 = feat[(size_t)s1 * DD + lane];
            acc = fmaf(f0, w0, acc);
            acc = fmaf(f1, w1, acc);
        }
        if (e < e1) acc = fmaf(feat[(size_t)ss[e] * DD + lane], ee[e], acc);
        float neigh = acc / fmaxf((float)(e1 - e0), 1.f);
        fs[wid][lane] = feat[(size_t)n * DD + lane];
        ns[wid][lane] = neigh;
        float o = bv;
#pragma unroll
        for (int k4 = 0; k4 < 16; ++k4) {
            float4 f = *(const float4*)&fs[wid][4 * k4];
            float4 nv = *(const float4*)&ns[wid][4 * k4];
            o = fmaf(wsr[4 * k4 + 0], f.x, o);
            o = fmaf(wsr[4 * k4 + 1], f.y, o);
            o = fmaf(wsr[4 * k4 + 2], f.z, o);
            o = fmaf(wsr[4 * k4 + 3], f.w, o);
            o = fmaf(wnr[4 * k4 + 0], nv.x, o);
            o = fmaf(wnr[4 * k4 + 1], nv.y, o);
            o = fmaf(wnr[4 * k4 + 2], nv.z, o);
            o = fmaf(wnr[4 * k4 + 3], nv.w, o);
        }
        o = fmaxf(o, 0.f);  // relu (layer 1)
        og[(size_t)n * DD + lane] = o;
    }
}

// ---------------------------------------------------------------- fused SAGE conv at candidate nodes only (layer 2)
__global__ __launch_bounds__(256) void k_conv_cand(
    const float* __restrict__ hfeat, const int* __restrict__ row_off,
    const int* __restrict__ srcs, const float* __restrict__ ews,
    const float* __restrict__ Wsf, const float* __restrict__ Wng,
    const float* __restrict__ bias, const int* __restrict__ cand,
    float* __restrict__ sel, int g0)
{
    const int gy = blockIdx.y;
    const int g = g0 + gy;
    const float* feat = hfeat + (size_t)gy * NN * DD;
    const int* ro = row_off + (size_t)gy * (NN + 1);
    const int* ss = srcs + (size_t)gy * NE;
    const float* ee = ews + (size_t)gy * NE;
    const int lane = threadIdx.x & 63;
    const int wid = threadIdx.x >> 6;

    float wsr[DD], wnr[DD];
    {
        const float* wsp = Wsf + (size_t)g * DD * DD + (size_t)lane * DD;
        const float* wnp = Wng + (size_t)g * DD * DD + (size_t)lane * DD;
#pragma unroll
        for (int k4 = 0; k4 < 16; ++k4) {
            float4 a = *(const float4*)(wsp + 4 * k4);
            wsr[4 * k4 + 0] = a.x; wsr[4 * k4 + 1] = a.y; wsr[4 * k4 + 2] = a.z; wsr[4 * k4 + 3] = a.w;
            float4 c = *(const float4*)(wnp + 4 * k4);
            wnr[4 * k4 + 0] = c.x; wnr[4 * k4 + 1] = c.y; wnr[4 * k4 + 2] = c.z; wnr[4 * k4 + 3] = c.w;
        }
    }
    const float bv = bias[(size_t)g * DD + lane];

    __shared__ __attribute__((aligned(16))) float fs[4][DD];
    __shared__ __attribute__((aligned(16))) float ns[4][DD];

    int t = blockIdx.x * 4 + wid;  // 0..1599
    if (t < NB_ * NL) {
        int b = t / NL;
        int l = t - b * NL;
        int n = cand[((size_t)b * NG + g) * NL + l];
        const int e0 = ro[n], e1 = ro[n + 1];
        float acc = 0.f;
        int e = e0;
        for (; e + 1 < e1; e += 2) {
            int s0 = ss[e], s1 = ss[e + 1];
            float w0 = ee[e], w1 = ee[e + 1];
            acc = fmaf(feat[(size_t)s0 * DD + lane], w0, acc);
            acc = fmaf(feat[(size_t)s1 * DD + lane], w1, acc);
        }
        if (e < e1) acc = fmaf(feat[(size_t)ss[e] * DD + lane], ee[e], acc);
        float neigh = acc / fmaxf((float)(e1 - e0), 1.f);
        fs[wid][lane] = feat[(size_t)n * DD + lane];
        ns[wid][lane] = neigh;
        float o = bv;
#pragma unroll
        for (int k4 = 0; k4 < 16; ++k4) {
            float4 f = *(const float4*)&fs[wid][4 * k4];
            float4 nv = *(const float4*)&ns[wid][4 * k4];
            o = fmaf(wsr[4 * k4 + 0], f.x, o);
            o = fmaf(wsr[4 * k4 + 1], f.y, o);
            o = fmaf(wsr[4 * k4 + 2], f.z, o);
            o = fmaf(wsr[4 * k4 + 3], f.w, o);
            o = fmaf(wnr[4 * k4 + 0], nv.x, o);
            o = fmaf(wnr[4 * k4 + 1], nv.y, o);
            o = fmaf(wnr[4 * k4 + 2], nv.z, o);
            o = fmaf(wnr[4 * k4 + 3], nv.w, o);
        }
        sel[(((size_t)b * NG + g) * NL + l) * DD + lane] = o;  // no relu
    }
}

// ---------------------------------------------------------------- attention stack 1: (B*G) blocks over (L=50, D=64)
__global__ __launch_bounds__(256) void k_attn1(
    const float* __restrict__ sel, const float* __restrict__ Q,
    const float* __restrict__ K, const float* __restrict__ V,
    float* __restrict__ xsum)
{
    __shared__ __attribute__((aligned(16))) float x[NL * DD];
    __shared__ __attribute__((aligned(16))) float qp[NL * 68];  // q rows, then P rows (in place)
    __shared__ __attribute__((aligned(16))) float kk[NL * 68];  // k rows, then Y rows
    const int tid = threadIdx.x;
    const int lane = tid & 63;
    const int wid = tid >> 6;
    const int bg = blockIdx.x;
    const float* xin = sel + (size_t)bg * NL * DD;
    for (int i = tid; i < NL * DD; i += 256) x[i] = xin[i];
    __syncthreads();

    for (int layer = 0; layer < NCL; ++layer) {
        const float* Qb = Q + (size_t)layer * DD * DD;
        const float* Kb = K + (size_t)layer * DD * DD;
        const float* Vb = V + (size_t)layer * DD * DD;
        float wrow[DD];
        // q = x @ Q.T
#pragma unroll
        for (int k4 = 0; k4 < 16; ++k4) {
            float4 a = *(const float4*)(Qb + (size_t)lane * DD + 4 * k4);
            wrow[4 * k4 + 0] = a.x; wrow[4 * k4 + 1] = a.y; wrow[4 * k4 + 2] = a.z; wrow[4 * k4 + 3] = a.w;
        }
        for (int l = wid; l < NL; l += 4) {
            float acc = 0.f;
#pragma unroll
            for (int k4 = 0; k4 < 16; ++k4) {
                float4 xv = *(const float4*)&x[l * DD + 4 * k4];
                acc = fmaf(wrow[4 * k4 + 0], xv.x, acc);
                acc = fmaf(wrow[4 * k4 + 1], xv.y, acc);
                acc = fmaf(wrow[4 * k4 + 2], xv.z, acc);
                acc = fmaf(wrow[4 * k4 + 3], xv.w, acc);
            }
            qp[l * 68 + lane] = acc;
        }
        // k = x @ K.T
#pragma unroll
        for (int k4 = 0; k4 < 16; ++k4) {
            float4 a = *(const float4*)(Kb + (size_t)lane * DD + 4 * k4);
            wrow[4 * k4 + 0] = a.x; wrow[4 * k4 + 1] = a.y; wrow[4 * k4 + 2] = a.z; wrow[4 * k4 + 3] = a.w;
        }
        for (int l = wid; l < NL; l += 4) {
            float acc = 0.f;
#pragma unroll
            for (int k4 = 0; k4 < 16; ++k4) {
                float4 xv = *(const float4*)&x[l * DD + 4 * k4];
                acc = fmaf(wrow[4 * k4 + 0], xv.x, acc);
                acc = fmaf(wrow[4 * k4 + 1], xv.y, acc);
                acc = fmaf(wrow[4 * k4 + 2], xv.z, acc);
                acc = fmaf(wrow[4 * k4 + 3], xv.w, acc);
            }
            kk[l * 68 + lane] = acc;
        }
        __syncthreads();
        // scores + softmax; P written into qp row (own wave's rows only)
        for (int l = wid; l < NL; l += 4) {
            float s;
            if (lane < NL) {
                float acc = 0.f;
#pragma unroll
                for (int k4 = 0; k4 < 16; ++k4) {
                    float4 qv = *(const float4*)&qp[l * 68 + 4 * k4];
                    float4 kv = *(const float4*)&kk[lane * 68 + 4 * k4];
                    acc += qv.x * kv.x + qv.y * kv.y + qv.z * kv.z + qv.w * kv.w;
                }
                s = acc * 0.125f;
            } else {
                s = -INFINITY;
            }
            float mx = s;
#pragma unroll
            for (int m = 32; m >= 1; m >>= 1) mx = fmaxf(mx, __shfl_xor(mx, m));
            float pe = __expf(s - mx);  // lanes >= 50 give 0
            float sm = pe;
#pragma unroll
            for (int m = 32; m >= 1; m >>= 1) sm += __shfl_xor(sm, m);
            qp[l * 68 + lane] = pe / sm;
        }
        __syncthreads();
        // Y = P @ X  -> kk
        for (int l = wid; l < NL; l += 4) {
            float acc = 0.f;
            for (int m = 0; m < NL; ++m)
                acc = fmaf(qp[l * 68 + m], x[m * DD + lane], acc);
            kk[l * 68 + lane] = acc;
        }
        __syncthreads();
        // out = Y @ V.T -> x
#pragma unroll
        for (int k4 = 0; k4 < 16; ++k4) {
            float4 a = *(const float4*)(Vb + (size_t)lane * DD + 4 * k4);
            wrow[4 * k4 + 0] = a.x; wrow[4 * k4 + 1] = a.y; wrow[4 * k4 + 2] = a.z; wrow[4 * k4 + 3] = a.w;
        }
        for (int l = wid; l < NL; l += 4) {
            float acc = 0.f;
#pragma unroll
            for (int k4 = 0; k4 < 16; ++k4) {
                float4 yv = *(const float4*)&kk[l * 68 + 4 * k4];
                acc = fmaf(wrow[4 * k4 + 0], yv.x, acc);
                acc = fmaf(wrow[4 * k4 + 1], yv.y, acc);
                acc = fmaf(wrow[4 * k4 + 2], yv.z, acc);
                acc = fmaf(wrow[4 * k4 + 3], yv.w, acc);
            }
            x[l * DD + lane] = acc;
        }
        __syncthreads();
    }
    if (wid == 0) {
        float acc = 0.f;
        for (int l = 0; l < NL; ++l) acc += x[l * DD + lane];
        xsum[(size_t)bg * DD + lane] = acc;
    }
}

// ---------------------------------------------------------------- attention stack 2: B blocks over (G=4, D=64)
__global__ __launch_bounds__(64) void k_attn2(
    const float* __restrict__ xin, const float* __restrict__ Q,
    const float* __restrict__ K, const float* __restrict__ V,
    float* __restrict__ out)
{
    __shared__ __attribute__((aligned(16))) float x[NG * DD];
    const int j = threadIdx.x;
    const int b = blockIdx.x;
    for (int i = j; i < NG * DD; i += 64) x[i] = xin[(size_t)b * NG * DD + i];
    __syncthreads();
    float o[NG];
    for (int layer = 0; layer < NCL; ++layer) {
        float wrow[DD];
        float q4[NG], k4v[NG], v4[NG];
        const float* Qb = Q + (size_t)layer * DD * DD + (size_t)j * DD;
        const float* Kb = K + (size_t)layer * DD * DD + (size_t)j * DD;
        const float* Vb = V + (size_t)layer * DD * DD + (size_t)j * DD;
#pragma unroll
        for (int k4 = 0; k4 < 16; ++k4) {
            float4 a = *(const float4*)(Qb + 4 * k4);
            wrow[4 * k4 + 0] = a.x; wrow[4 * k4 + 1] = a.y; wrow[4 * k4 + 2] = a.z; wrow[4 * k4 + 3] = a.w;
        }
#pragma unroll
        for (int g = 0; g < NG; ++g) {
            float acc = 0.f;
#pragma unroll
            for (int k4 = 0; k4 < 16; ++k4) {
                float4 xv = *(const float4*)&x[g * DD + 4 * k4];
                acc = fmaf(wrow[4 * k4 + 0], xv.x, acc);
                acc = fmaf(wrow[4 * k4 + 1], xv.y, acc);
                acc = fmaf(wrow[4 * k4 + 2], xv.z, acc);
                acc = fmaf(wrow[4 * k4 + 3], xv.w, acc);
            }
            q4[g] = acc;
        }
#pragma unroll
        for (int k4 = 0; k4 < 16; ++k4) {
            float4 a = *(const float4*)(Kb + 4 * k4);
            wrow[4 * k4 + 0] = a.x; wrow[4 * k4 + 1] = a.y; wrow[4 * k4 + 2] = a.z; wrow[4 * k4 + 3] = a.w;
        }
#pragma unroll
        for (int g = 0; g < NG; ++g) {
            float acc = 0.f;
#pragma unroll
            for (int k4 = 0; k4 < 16; ++k4) {
                float4 xv = *(const float4*)&x[g * DD + 4 * k4];
                acc = fmaf(wrow[4 * k4 + 0], xv.x, acc);
                acc = fmaf(wrow[4 * k4 + 1], xv.y, acc);
                acc = fmaf(wrow[4 * k4 + 2], xv.z, acc);
                acc = fmaf(wrow[4 * k4 + 3], xv.w, acc);
            }
            k4v[g] = acc;
        }
#pragma unroll
        for (int k4 = 0; k4 < 16; ++k4) {
            float4 a = *(const float4*)(Vb + 4 * k4);
            wrow[4 * k4 + 0] = a.x; wrow[4 * k4 + 1] = a.y; wrow[4 * k4 + 2] = a.z; wrow[4 * k4 + 3] = a.w;
        }
#pragma unroll
        for (int g = 0; g < NG; ++g) {
            float acc = 0.f;
#pragma unroll
            for (int k4 = 0; k4 < 16; ++k4) {
                float4 xv = *(const float4*)&x[g * DD + 4 * k4];
                acc = fmaf(wrow[4 * k4 + 0], xv.x, acc);
                acc = fmaf(wrow[4 * k4 + 1], xv.y, acc);
                acc = fmaf(wrow[4 * k4 + 2], xv.z, acc);
                acc = fmaf(wrow[4 * k4 + 3], xv.w, acc);
            }
            v4[g] = acc;
        }
        // scores via full-wave reduction over the feature lanes
        float p[NG][NG];
#pragma unroll
        for (int l = 0; l < NG; ++l) {
#pragma unroll
            for (int m = 0; m < NG; ++m) {
                float t = q4[l] * k4v[m];
#pragma unroll
                for (int mk = 32; mk >= 1; mk >>= 1) t += __shfl_xor(t, mk);
                p[l][m] = t * 0.125f;
            }
        }
#pragma unroll
        for (int l = 0; l < NG; ++l) {
            float mx = fmaxf(fmaxf(p[l][0], p[l][1]), fmaxf(p[l][2], p[l][3]));
            float e0 = __expf(p[l][0] - mx), e1 = __expf(p[l][1] - mx);
            float e2 = __expf(p[l][2] - mx), e3 = __expf(p[l][3] - mx);
            float inv = 1.f / (e0 + e1 + e2 + e3);
            o[l] = (e0 * v4[0] + e1 * v4[1] + e2 * v4[2] + e3 * v4[3]) * inv;
        }
        __syncthreads();
#pragma unroll
        for (int l = 0; l < NG; ++l) x[l * DD + j] = o[l];
        __syncthreads();
    }
    out[(size_t)b * DD + j] = o[0] + o[1] + o[2] + o[3];
}

// ---------------------------------------------------------------- host
extern "C" void kernel_launch(void* const* d_in, const int* in_sizes, int n_in,
                              void* d_out, int out_size, void* d_ws, size_t ws_size,
                              hipStream_t stream)
{
    const int*   src  = (const int*)  d_in[0];
    const int*   dst  = (const int*)  d_in[1];
    const float* ew   = (const float*)d_in[2];
    const float* emb  = (const float*)d_in[3];
    const float* Ws1  = (const float*)d_in[4];
    const float* Wn1  = (const float*)d_in[5];
    const float* b1   = (const float*)d_in[6];
    const float* Ws2  = (const float*)d_in[7];
    const float* Wn2  = (const float*)d_in[8];
    const float* b2   = (const float*)d_in[9];
    const float* Q1   = (const float*)d_in[10];
    const float* K1   = (const float*)d_in[11];
    const float* V1   = (const float*)d_in[12];
    const float* Q2   = (const float*)d_in[13];
    const float* K2   = (const float*)d_in[14];
    const float* V2   = (const float*)d_in[15];
    const int*   cand = (const int*)  d_in[16];
    float* out = (float*)d_out;

    auto padded = [](size_t b) { return (b + 255) & ~(size_t)255; };
    auto need = [&](int GG) -> size_t {
        size_t s = 0;
        s += padded((size_t)GG * (NN + 1) * 4);   // cnt
        s += padded((size_t)GG * 64 * 4);         // partials
        s += padded((size_t)GG * (NN + 1) * 4);   // row_off
        s += padded((size_t)GG * NN * 4);         // cursor
        s += padded((size_t)GG * NE * 4);         // src_sorted
        s += padded((size_t)GG * NE * 4);         // ew_sorted
        s += padded((size_t)GG * NN * DD * 4);    // h
        s += padded((size_t)NB_ * NG * NL * DD * 4); // sel
        s += padded((size_t)NB_ * NG * DD * 4);      // xsum
        return s;
    };
    const int GG = (ws_size >= need(4)) ? 4 : 1;

    char* p = (char*)d_ws;
    auto alloc = [&](size_t b) -> void* { void* r = (void*)p; p += padded(b); return r; };
    int*   cnt  = (int*)  alloc((size_t)GG * (NN + 1) * 4);
    int*   part = (int*)  alloc((size_t)GG * 64 * 4);
    int*   roff = (int*)  alloc((size_t)GG * (NN + 1) * 4);
    int*   cur  = (int*)  alloc((size_t)GG * NN * 4);
    int*   ssb  = (int*)  alloc((size_t)GG * NE * 4);
    float* eeb  = (float*)alloc((size_t)GG * NE * 4);
    float* hb   = (float*)alloc((size_t)GG * NN * DD * 4);
    float* sel  = (float*)alloc((size_t)NB_ * NG * NL * DD * 4);
    float* xsum = (float*)alloc((size_t)NB_ * NG * DD * 4);

    for (int g0 = 0; g0 < NG; g0 += GG) {
        hipMemsetAsync(cnt, 0, (size_t)GG * (NN + 1) * 4, stream);
        k_hist   <<<dim3(NE / 256, GG), 256, 0, stream>>>(dst, cnt, g0);
        k_scan1  <<<dim3(SCAN_NB, GG), 256, 0, stream>>>(cnt, part);
        k_scan2  <<<dim3(1, GG), 64, 0, stream>>>(part, roff);
        k_scan3  <<<dim3(SCAN_NB, GG), 256, 0, stream>>>(cnt, part, roff, cur);
        k_scatter<<<dim3(NE / 256, GG), 256, 0, stream>>>(src, dst, ew, cur, ssb, eeb, g0);
        k_conv_full<<<dim3(2048, GG), 256, 0, stream>>>(emb, roff, ssb, eeb, Ws1, Wn1, b1, hb, g0);
        k_conv_cand<<<dim3((NB_ * NL) / 4, GG), 256, 0, stream>>>(hb, roff, ssb, eeb, Ws2, Wn2, b2, cand, sel, g0);
    }
    k_attn1<<<NB_ * NG, 256, 0, stream>>>(sel, Q1, K1, V1, xsum);
    k_attn2<<<NB_, 64, 0, stream>>>(xsum, Q2, K2, V2, out);
}

// Round 2
// 1207.662 us; speedup vs baseline: 1.4714x; 1.4714x over previous
//
#include <hip/hip_runtime.h>
#include <cstdint>
#include <cstddef>
#include <cmath>

#define NN   100000   // nodes per graph
#define NE   1600000  // edges per graph
#define DD   64       // feature dim
#define NG   4        // graphs
#define NB_  32       // batch
#define NL   50       // candidate list length
#define NCL  2        // attention layers per stack
#define SCAN_NB 49    // ceil(NN/2048)

// ---------------------------------------------------------------- CSR build
__global__ __launch_bounds__(256) void k_hist(const int* __restrict__ dst,
                                              int* __restrict__ cnt, int g0) {
    const int gy = blockIdx.y;
    const int* d = dst + (size_t)(g0 + gy) * NE;
    int* c = cnt + (size_t)gy * (NN + 1);
    int e = blockIdx.x * 256 + threadIdx.x;
    if (e < NE) atomicAdd(&c[d[e]], 1);
}

__global__ __launch_bounds__(256) void k_scan1(const int* __restrict__ cnt,
                                               int* __restrict__ part) {
    const int gy = blockIdx.y;
    const int* c = cnt + (size_t)gy * (NN + 1);
    __shared__ int sh[256];
    const int tid = threadIdx.x;
    int base = blockIdx.x * 2048 + tid * 8;
    int s = 0;
    for (int i = 0; i < 8; ++i) { int idx = base + i; if (idx < NN) s += c[idx]; }
    sh[tid] = s; __syncthreads();
    for (int off = 128; off > 0; off >>= 1) {
        if (tid < off) sh[tid] += sh[tid + off];
        __syncthreads();
    }
    if (tid == 0) part[gy * 64 + blockIdx.x] = sh[0];
}

__global__ __launch_bounds__(64) void k_scan2(int* __restrict__ part,
                                              int* __restrict__ row_off) {
    const int gy = blockIdx.y;
    if (threadIdx.x == 0) {
        int* p = part + gy * 64;
        int run = 0;
        for (int i = 0; i < SCAN_NB; ++i) { int t = p[i]; p[i] = run; run += t; }
        row_off[(size_t)gy * (NN + 1) + NN] = run;  // == NE
    }
}

__global__ __launch_bounds__(256) void k_scan3(const int* __restrict__ cnt,
                                               const int* __restrict__ part,
                                               int* __restrict__ row_off,
                                               int* __restrict__ cursor) {
    const int gy = blockIdx.y;
    const int* c = cnt + (size_t)gy * (NN + 1);
    int* ro = row_off + (size_t)gy * (NN + 1);
    int* cu = cursor + (size_t)gy * NN;
    __shared__ int sh[256];
    const int tid = threadIdx.x;
    int base = blockIdx.x * 2048 + tid * 8;
    int vals[8];
    int s = 0;
    for (int i = 0; i < 8; ++i) {
        int idx = base + i;
        int v = (idx < NN) ? c[idx] : 0;
        vals[i] = v; s += v;
    }
    sh[tid] = s; __syncthreads();
    for (int off = 1; off < 256; off <<= 1) {
        int t = (tid >= off) ? sh[tid - off] : 0;
        __syncthreads();
        sh[tid] += t;
        __syncthreads();
    }
    int excl = sh[tid] - s;
    int run = part[gy * 64 + blockIdx.x] + excl;
    for (int i = 0; i < 8; ++i) {
        int idx = base + i;
        if (idx < NN) { ro[idx] = run; cu[idx] = run; run += vals[i]; }
    }
}

// scatter: one packed 8B record per edge (src, ew-bits) — halves the random-write
// transactions vs two 4B stores to separate arrays
__global__ __launch_bounds__(256) void k_scatter(const int* __restrict__ src,
                                                 const int* __restrict__ dst,
                                                 const float* __restrict__ ew,
                                                 int* __restrict__ cursor,
                                                 int2* __restrict__ ed, int g0) {
    const int gy = blockIdx.y;
    const int g = g0 + gy;
    int e = blockIdx.x * 256 + threadIdx.x;
    if (e < NE) {
        int d = dst[(size_t)g * NE + e];
        int p = atomicAdd(&cursor[(size_t)gy * NN + d], 1);
        ed[(size_t)gy * NE + p] = make_int2(src[(size_t)g * NE + e],
                                            __float_as_int(ew[(size_t)g * NE + e]));
    }
}

// ---------------------------------------------------------------- fused SAGE conv (all nodes, layer 1, relu)
// Gather restructured for MLP: cooperative chunk load of up to 64 edge records
// (lane = edge), shuffle-broadcast indices, then 8 independent feat-row gathers
// in flight per group. No load->load dependency chain.
__global__ __launch_bounds__(256) void k_conv_full(
    const float* __restrict__ emb, const int* __restrict__ row_off,
    const int2* __restrict__ edges,
    const float* __restrict__ Wsf, const float* __restrict__ Wng,
    const float* __restrict__ bias, float* __restrict__ outh, int g0)
{
    const int gy = blockIdx.y;
    const int g = g0 + gy;
    const float* feat = emb + (size_t)g * NN * DD;
    const int* ro = row_off + (size_t)gy * (NN + 1);
    const int2* ed = edges + (size_t)gy * NE;
    float* og = outh + (size_t)gy * NN * DD;
    const int lane = threadIdx.x & 63;
    const int wid = threadIdx.x >> 6;

    float wsr[DD], wnr[DD];
    {
        const float* wsp = Wsf + (size_t)g * DD * DD + (size_t)lane * DD;
        const float* wnp = Wng + (size_t)g * DD * DD + (size_t)lane * DD;
#pragma unroll
        for (int k4 = 0; k4 < 16; ++k4) {
            float4 a = *(const float4*)(wsp + 4 * k4);
            wsr[4 * k4 + 0] = a.x; wsr[4 * k4 + 1] = a.y; wsr[4 * k4 + 2] = a.z; wsr[4 * k4 + 3] = a.w;
            float4 c = *(const float4*)(wnp + 4 * k4);
            wnr[4 * k4 + 0] = c.x; wnr[4 * k4 + 1] = c.y; wnr[4 * k4 + 2] = c.z; wnr[4 * k4 + 3] = c.w;
        }
    }
    const float bv = bias[(size_t)g * DD + lane];

    __shared__ __attribute__((aligned(16))) float fs[4][DD];
    __shared__ __attribute__((aligned(16))) float ns[4][DD];

    const int wglob = blockIdx.x * 4 + wid;
    const int wstep = gridDim.x * 4;
    for (int n = wglob; n < NN; n += wstep) {
        const int e0 = ro[n], e1 = ro[n + 1];
        const float fself = feat[(size_t)n * DD + lane];  // issue early
        float acc = 0.f;
        for (int base = e0; base < e1; base += 64) {
            const int cnt = min(e1 - base, 64);
            int   myS = 0;
            float myW = 0.f;
            if (lane < cnt) {
                int2 r = ed[base + lane];
                myS = r.x; myW = __int_as_float(r.y);
            }
            for (int j = 0; j < cnt; j += 8) {
                float fv[8], wv[8];
#pragma unroll
                for (int u = 0; u < 8; ++u) {
                    int s = __shfl(myS, j + u);        // padded lanes give s=0, w=0
                    wv[u] = __shfl(myW, j + u);
                    fv[u] = feat[(size_t)s * DD + lane];
                }
#pragma unroll
                for (int u = 0; u < 8; ++u) acc = fmaf(fv[u], wv[u], acc);
            }
        }
        float neigh = acc / fmaxf((float)(e1 - e0), 1.f);
        fs[wid][lane] = fself;
        ns[wid][lane] = neigh;
        float o = bv;
#pragma unroll
        for (int k4 = 0; k4 < 16; ++k4) {
            float4 f = *(const float4*)&fs[wid][4 * k4];
            float4 nv = *(const float4*)&ns[wid][4 * k4];
            o = fmaf(wsr[4 * k4 + 0], f.x, o);
            o = fmaf(wsr[4 * k4 + 1], f.y, o);
            o = fmaf(wsr[4 * k4 + 2], f.z, o);
            o = fmaf(wsr[4 * k4 + 3], f.w, o);
            o = fmaf(wnr[4 * k4 + 0], nv.x, o);
            o = fmaf(wnr[4 * k4 + 1], nv.y, o);
            o = fmaf(wnr[4 * k4 + 2], nv.z, o);
            o = fmaf(wnr[4 * k4 + 3], nv.w, o);
        }
        o = fmaxf(o, 0.f);  // relu (layer 1)
        og[(size_t)n * DD + lane] = o;
    }
}

// ---------------------------------------------------------------- fused SAGE conv at candidate nodes only (layer 2)
__global__ __launch_bounds__(256) void k_conv_cand(
    const float* __restrict__ hfeat, const int* __restrict__ row_off,
    const int2* __restrict__ edges,
    const float* __restrict__ Wsf, const float* __restrict__ Wng,
    const float* __restrict__ bias, const int* __restrict__ cand,
    float* __restrict__ sel, int g0)
{
    const int gy = blockIdx.y;
    const int g = g0 + gy;
    const float* feat = hfeat + (size_t)gy * NN * DD;
    const int* ro = row_off + (size_t)gy * (NN + 1);
    const int2* ed = edges + (size_t)gy * NE;
    const int lane = threadIdx.x & 63;
    const int wid = threadIdx.x >> 6;

    float wsr[DD], wnr[DD];
    {
        const float* wsp = Wsf + (size_t)g * DD * DD + (size_t)lane * DD;
        const float* wnp = Wng + (size_t)g * DD * DD + (size_t)lane * DD;
#pragma unroll
        for (int k4 = 0; k4 < 16; ++k4) {
            float4 a = *(const float4*)(wsp + 4 * k4);
            wsr[4 * k4 + 0] = a.x; wsr[4 * k4 + 1] = a.y; wsr[4 * k4 + 2] = a.z; wsr[4 * k4 + 3] = a.w;
            float4 c = *(const float4*)(wnp + 4 * k4);
            wnr[4 * k4 + 0] = c.x; wnr[4 * k4 + 1] = c.y; wnr[4 * k4 + 2] = c.z; wnr[4 * k4 + 3] = c.w;
        }
    }
    const float bv = bias[(size_t)g * DD + lane];

    __shared__ __attribute__((aligned(16))) float fs[4][DD];
    __shared__ __attribute__((aligned(16))) float ns[4][DD];

    int t = blockIdx.x * 4 + wid;  // 0..1599
    if (t < NB_ * NL) {
        int b = t / NL;
        int l = t - b * NL;
        int n = cand[((size_t)b * NG + g) * NL + l];
        const int e0 = ro[n], e1 = ro[n + 1];
        const float fself = feat[(size_t)n * DD + lane];
        float acc = 0.f;
        for (int base = e0; base < e1; base += 64) {
            const int cnt = min(e1 - base, 64);
            int   myS = 0;
            float myW = 0.f;
            if (lane < cnt) {
                int2 r = ed[base + lane];
                myS = r.x; myW = __int_as_float(r.y);
            }
            for (int j = 0; j < cnt; j += 8) {
                float fv[8], wv[8];
#pragma unroll
                for (int u = 0; u < 8; ++u) {
                    int s = __shfl(myS, j + u);
                    wv[u] = __shfl(myW, j + u);
                    fv[u] = feat[(size_t)s * DD + lane];
                }
#pragma unroll
                for (int u = 0; u < 8; ++u) acc = fmaf(fv[u], wv[u], acc);
            }
        }
        float neigh = acc / fmaxf((float)(e1 - e0), 1.f);
        fs[wid][lane] = fself;
        ns[wid][lane] = neigh;
        float o = bv;
#pragma unroll
        for (int k4 = 0; k4 < 16; ++k4) {
            float4 f = *(const float4*)&fs[wid][4 * k4];
            float4 nv = *(const float4*)&ns[wid][4 * k4];
            o = fmaf(wsr[4 * k4 + 0], f.x, o);
            o = fmaf(wsr[4 * k4 + 1], f.y, o);
            o = fmaf(wsr[4 * k4 + 2], f.z, o);
            o = fmaf(wsr[4 * k4 + 3], f.w, o);
            o = fmaf(wnr[4 * k4 + 0], nv.x, o);
            o = fmaf(wnr[4 * k4 + 1], nv.y, o);
            o = fmaf(wnr[4 * k4 + 2], nv.z, o);
            o = fmaf(wnr[4 * k4 + 3], nv.w, o);
        }
        sel[(((size_t)b * NG + g) * NL + l) * DD + lane] = o;  // no relu
    }
}

// ---------------------------------------------------------------- attention stack 1: (B*G) blocks over (L=50, D=64)
__global__ __launch_bounds__(256) void k_attn1(
    const float* __restrict__ sel, const float* __restrict__ Q,
    const float* __restrict__ K, const float* __restrict__ V,
    float* __restrict__ xsum)
{
    __shared__ __attribute__((aligned(16))) float x[NL * DD];
    __shared__ __attribute__((aligned(16))) float qp[NL * 68];  // q rows, then P rows (in place)
    __shared__ __attribute__((aligned(16))) float kk[NL * 68];  // k rows, then Y rows
    const int tid = threadIdx.x;
    const int lane = tid & 63;
    const int wid = tid >> 6;
    const int bg = blockIdx.x;
    const float* xin = sel + (size_t)bg * NL * DD;
    for (int i = tid; i < NL * DD; i += 256) x[i] = xin[i];
    __syncthreads();

    for (int layer = 0; layer < NCL; ++layer) {
        const float* Qb = Q + (size_t)layer * DD * DD;
        const float* Kb = K + (size_t)layer * DD * DD;
        const float* Vb = V + (size_t)layer * DD * DD;
        float wrow[DD];
        // q = x @ Q.T
#pragma unroll
        for (int k4 = 0; k4 < 16; ++k4) {
            float4 a = *(const float4*)(Qb + (size_t)lane * DD + 4 * k4);
            wrow[4 * k4 + 0] = a.x; wrow[4 * k4 + 1] = a.y; wrow[4 * k4 + 2] = a.z; wrow[4 * k4 + 3] = a.w;
        }
        for (int l = wid; l < NL; l += 4) {
            float acc = 0.f;
#pragma unroll
            for (int k4 = 0; k4 < 16; ++k4) {
                float4 xv = *(const float4*)&x[l * DD + 4 * k4];
                acc = fmaf(wrow[4 * k4 + 0], xv.x, acc);
                acc = fmaf(wrow[4 * k4 + 1], xv.y, acc);
                acc = fmaf(wrow[4 * k4 + 2], xv.z, acc);
                acc = fmaf(wrow[4 * k4 + 3], xv.w, acc);
            }
            qp[l * 68 + lane] = acc;
        }
        // k = x @ K.T
#pragma unroll
        for (int k4 = 0; k4 < 16; ++k4) {
            float4 a = *(const float4*)(Kb + (size_t)lane * DD + 4 * k4);
            wrow[4 * k4 + 0] = a.x; wrow[4 * k4 + 1] = a.y; wrow[4 * k4 + 2] = a.z; wrow[4 * k4 + 3] = a.w;
        }
        for (int l = wid; l < NL; l += 4) {
            float acc = 0.f;
#pragma unroll
            for (int k4 = 0; k4 < 16; ++k4) {
                float4 xv = *(const float4*)&x[l * DD + 4 * k4];
                acc = fmaf(wrow[4 * k4 + 0], xv.x, acc);
                acc = fmaf(wrow[4 * k4 + 1], xv.y, acc);
                acc = fmaf(wrow[4 * k4 + 2], xv.z, acc);
                acc = fmaf(wrow[4 * k4 + 3], xv.w, acc);
            }
            kk[l * 68 + lane] = acc;
        }
        __syncthreads();
        // scores + softmax; P written into qp row (own wave's rows only)
        for (int l = wid; l < NL; l += 4) {
            float s;
            if (lane < NL) {
                float acc = 0.f;
#pragma unroll
                for (int k4 = 0; k4 < 16; ++k4) {
                    float4 qv = *(const float4*)&qp[l * 68 + 4 * k4];
                    float4 kv = *(const float4*)&kk[lane * 68 + 4 * k4];
                    acc += qv.x * kv.x + qv.y * kv.y + qv.z * kv.z + qv.w * kv.w;
                }
                s = acc * 0.125f;
            } else {
                s = -INFINITY;
            }
            float mx = s;
#pragma unroll
            for (int m = 32; m >= 1; m >>= 1) mx = fmaxf(mx, __shfl_xor(mx, m));
            float pe = __expf(s - mx);  // lanes >= 50 give 0
            float sm = pe;
#pragma unroll
            for (int m = 32; m >= 1; m >>= 1) sm += __shfl_xor(sm, m);
            qp[l * 68 + lane] = pe / sm;
        }
        __syncthreads();
        // Y = P @ X  -> kk
        for (int l = wid; l < NL; l += 4) {
            float acc = 0.f;
            for (int m = 0; m < NL; ++m)
                acc = fmaf(qp[l * 68 + m], x[m * DD + lane], acc);
            kk[l * 68 + lane] = acc;
        }
        __syncthreads();
        // out = Y @ V.T -> x
#pragma unroll
        for (int k4 = 0; k4 < 16; ++k4) {
            float4 a = *(const float4*)(Vb + (size_t)lane * DD + 4 * k4);
            wrow[4 * k4 + 0] = a.x; wrow[4 * k4 + 1] = a.y; wrow[4 * k4 + 2] = a.z; wrow[4 * k4 + 3] = a.w;
        }
        for (int l = wid; l < NL; l += 4) {
            float acc = 0.f;
#pragma unroll
            for (int k4 = 0; k4 < 16; ++k4) {
                float4 yv = *(const float4*)&kk[l * 68 + 4 * k4];
                acc = fmaf(wrow[4 * k4 + 0], yv.x, acc);
                acc = fmaf(wrow[4 * k4 + 1], yv.y, acc);
                acc = fmaf(wrow[4 * k4 + 2], yv.z, acc);
                acc = fmaf(wrow[4 * k4 + 3], yv.w, acc);
            }
            x[l * DD + lane] = acc;
        }
        __syncthreads();
    }
    if (wid == 0) {
        float acc = 0.f;
        for (int l = 0; l < NL; ++l) acc += x[l * DD + lane];
        xsum[(size_t)bg * DD + lane] = acc;
    }
}

// ---------------------------------------------------------------- attention stack 2: B blocks over (G=4, D=64)
__global__ __launch_bounds__(64) void k_attn2(
    const float* __restrict__ xin, const float* __restrict__ Q,
    const float* __restrict__ K, const float* __restrict__ V,
    float* __restrict__ out)
{
    __shared__ __attribute__((aligned(16))) float x[NG * DD];
    const int j = threadIdx.x;
    const int b = blockIdx.x;
    for (int i = j; i < NG * DD; i += 64) x[i] = xin[(size_t)b * NG * DD + i];
    __syncthreads();
    float o[NG];
    for (int layer = 0; layer < NCL; ++layer) {
        float wrow[DD];
        float q4[NG], k4v[NG], v4[NG];
        const float* Qb = Q + (size_t)layer * DD * DD + (size_t)j * DD;
        const float* Kb = K + (size_t)layer * DD * DD + (size_t)j * DD;
        const float* Vb = V + (size_t)layer * DD * DD + (size_t)j * DD;
#pragma unroll
        for (int k4 = 0; k4 < 16; ++k4) {
            float4 a = *(const float4*)(Qb + 4 * k4);
            wrow[4 * k4 + 0] = a.x; wrow[4 * k4 + 1] = a.y; wrow[4 * k4 + 2] = a.z; wrow[4 * k4 + 3] = a.w;
        }
#pragma unroll
        for (int g = 0; g < NG; ++g) {
            float acc = 0.f;
#pragma unroll
            for (int k4 = 0; k4 < 16; ++k4) {
                float4 xv = *(const float4*)&x[g * DD + 4 * k4];
                acc = fmaf(wrow[4 * k4 + 0], xv.x, acc);
                acc = fmaf(wrow[4 * k4 + 1], xv.y, acc);
                acc = fmaf(wrow[4 * k4 + 2], xv.z, acc);
                acc = fmaf(wrow[4 * k4 + 3], xv.w, acc);
            }
            q4[g] = acc;
        }
#pragma unroll
        for (int k4 = 0; k4 < 16; ++k4) {
            float4 a = *(const float4*)(Kb + 4 * k4);
            wrow[4 * k4 + 0] = a.x; wrow[4 * k4 + 1] = a.y; wrow[4 * k4 + 2] = a.z; wrow[4 * k4 + 3] = a.w;
        }
#pragma unroll
        for (int g = 0; g < NG; ++g) {
            float acc = 0.f;
#pragma unroll
            for (int k4 = 0; k4 < 16; ++k4) {
                float4 xv = *(const float4*)&x[g * DD + 4 * k4];
                acc = fmaf(wrow[4 * k4 + 0], xv.x, acc);
                acc = fmaf(wrow[4 * k4 + 1], xv.y, acc);
                acc = fmaf(wrow[4 * k4 + 2], xv.z, acc);
                acc = fmaf(wrow[4 * k4 + 3], xv.w, acc);
            }
            k4v[g] = acc;
        }
#pragma unroll
        for (int k4 = 0; k4 < 16; ++k4) {
            float4 a = *(const float4*)(Vb + 4 * k4);
            wrow[4 * k4 + 0] = a.x; wrow[4 * k4 + 1] = a.y; wrow[4 * k4 + 2] = a.z; wrow[4 * k4 + 3] = a.w;
        }
#pragma unroll
        for (int g = 0; g < NG; ++g) {
            float acc = 0.f;
#pragma unroll
            for (int k4 = 0; k4 < 16; ++k4) {
                float4 xv = *(const float4*)&x[g * DD + 4 * k4];
                acc = fmaf(wrow[4 * k4 + 0], xv.x, acc);
                acc = fmaf(wrow[4 * k4 + 1], xv.y, acc);
                acc = fmaf(wrow[4 * k4 + 2], xv.z, acc);
                acc = fmaf(wrow[4 * k4 + 3], xv.w, acc);
            }
            v4[g] = acc;
        }
        // scores via full-wave reduction over the feature lanes
        float p[NG][NG];
#pragma unroll
        for (int l = 0; l < NG; ++l) {
#pragma unroll
            for (int m = 0; m < NG; ++m) {
                float t = q4[l] * k4v[m];
#pragma unroll
                for (int mk = 32; mk >= 1; mk >>= 1) t += __shfl_xor(t, mk);
                p[l][m] = t * 0.125f;
            }
        }
#pragma unroll
        for (int l = 0; l < NG; ++l) {
            float mx = fmaxf(fmaxf(p[l][0], p[l][1]), fmaxf(p[l][2], p[l][3]));
            float e0 = __expf(p[l][0] - mx), e1 = __expf(p[l][1] - mx);
            float e2 = __expf(p[l][2] - mx), e3 = __expf(p[l][3] - mx);
            float inv = 1.f / (e0 + e1 + e2 + e3);
            o[l] = (e0 * v4[0] + e1 * v4[1] + e2 * v4[2] + e3 * v4[3]) * inv;
        }
        __syncthreads();
#pragma unroll
        for (int l = 0; l < NG; ++l) x[l * DD + j] = o[l];
        __syncthreads();
    }
    out[(size_t)b * DD + j] = o[0] + o[1] + o[2] + o[3];
}

// ---------------------------------------------------------------- host
extern "C" void kernel_launch(void* const* d_in, const int* in_sizes, int n_in,
                              void* d_out, int out_size, void* d_ws, size_t ws_size,
                              hipStream_t stream)
{
    const int*   src  = (const int*)  d_in[0];
    const int*   dst  = (const int*)  d_in[1];
    const float* ew   = (const float*)d_in[2];
    const float* emb  = (const float*)d_in[3];
    const float* Ws1  = (const float*)d_in[4];
    const float* Wn1  = (const float*)d_in[5];
    const float* b1   = (const float*)d_in[6];
    const float* Ws2  = (const float*)d_in[7];
    const float* Wn2  = (const float*)d_in[8];
    const float* b2   = (const float*)d_in[9];
    const float* Q1   = (const float*)d_in[10];
    const float* K1   = (const float*)d_in[11];
    const float* V1   = (const float*)d_in[12];
    const float* Q2   = (const float*)d_in[13];
    const float* K2   = (const float*)d_in[14];
    const float* V2   = (const float*)d_in[15];
    const int*   cand = (const int*)  d_in[16];
    float* out = (float*)d_out;

    auto padded = [](size_t b) { return (b + 255) & ~(size_t)255; };
    auto need = [&](int GG) -> size_t {
        size_t s = 0;
        s += padded((size_t)GG * (NN + 1) * 4);   // cnt
        s += padded((size_t)GG * 64 * 4);         // partials
        s += padded((size_t)GG * (NN + 1) * 4);   // row_off
        s += padded((size_t)GG * NN * 4);         // cursor
        s += padded((size_t)GG * NE * 8);         // packed edges
        s += padded((size_t)GG * NN * DD * 4);    // h
        s += padded((size_t)NB_ * NG * NL * DD * 4); // sel
        s += padded((size_t)NB_ * NG * DD * 4);      // xsum
        return s;
    };
    const int GG = (ws_size >= need(4)) ? 4 : 1;

    char* p = (char*)d_ws;
    auto alloc = [&](size_t b) -> void* { void* r = (void*)p; p += padded(b); return r; };
    int*   cnt  = (int*)  alloc((size_t)GG * (NN + 1) * 4);
    int*   part = (int*)  alloc((size_t)GG * 64 * 4);
    int*   roff = (int*)  alloc((size_t)GG * (NN + 1) * 4);
    int*   cur  = (int*)  alloc((size_t)GG * NN * 4);
    int2*  edg  = (int2*) alloc((size_t)GG * NE * 8);
    float* hb   = (float*)alloc((size_t)GG * NN * DD * 4);
    float* sel  = (float*)alloc((size_t)NB_ * NG * NL * DD * 4);
    float* xsum = (float*)alloc((size_t)NB_ * NG * DD * 4);

    for (int g0 = 0; g0 < NG; g0 += GG) {
        hipMemsetAsync(cnt, 0, (size_t)GG * (NN + 1) * 4, stream);
        k_hist   <<<dim3(NE / 256, GG), 256, 0, stream>>>(dst, cnt, g0);
        k_scan1  <<<dim3(SCAN_NB, GG), 256, 0, stream>>>(cnt, part);
        k_scan2  <<<dim3(1, GG), 64, 0, stream>>>(part, roff);
        k_scan3  <<<dim3(SCAN_NB, GG), 256, 0, stream>>>(cnt, part, roff, cur);
        k_scatter<<<dim3(NE / 256, GG), 256, 0, stream>>>(src, dst, ew, cur, edg, g0);
        k_conv_full<<<dim3(2048, GG), 256, 0, stream>>>(emb, roff, edg, Ws1, Wn1, b1, hb, g0);
        k_conv_cand<<<dim3((NB_ * NL) / 4, GG), 256, 0, stream>>>(hb, roff, edg, Ws2, Wn2, b2, cand, sel, g0);
    }
    k_attn1<<<NB_ * NG, 256, 0, stream>>>(sel, Q1, K1, V1, xsum);
    k_attn2<<<NB_, 64, 0, stream>>>(xsum, Q2, K2, V2, out);
}